// Round 1
// baseline (508.892 us; speedup 1.0000x reference)
//
#include <hip/hip_runtime.h>
#include <hip/hip_bf16.h>

namespace {

constexpr int E_DIM = 512;
constexpr int NH = 8;
constexpr int HD = 64;
constexpr int LQ = 1024;
constexpr int LKV = 4096;
constexpr int NB = 4;

typedef __attribute__((ext_vector_type(8))) short bf16x8;
typedef __attribute__((ext_vector_type(8))) unsigned short u16x8;
typedef __attribute__((ext_vector_type(4))) float f32x4;

__device__ __forceinline__ f32x4 mfma16(bf16x8 a, bf16x8 b, f32x4 c) {
  return __builtin_amdgcn_mfma_f32_16x16x32_bf16(a, b, c, 0, 0, 0);
}

// f32 -> bf16 bits, round-to-nearest-even (finite inputs only)
__device__ __forceinline__ unsigned short f2b(float f) {
  unsigned int u = __float_as_uint(f);
  u += 0x7FFFu + ((u >> 16) & 1u);
  return (unsigned short)(u >> 16);
}

// out[i,j] = sum_k X[i,k]*W[j,k] + bias[j]   (N = K = 512)
// EPI 0: bf16 head-split  out[((b*NH+h)*L + l)*64 + d]
// EPI 1: bf16 head-split transposed  out[((b*NH+h)*64 + d)*L + l]
// EPI 2: f32 plain  out[i*512 + j]
template <int EPI>
__global__ __launch_bounds__(256) void gemm_proj(
    const float* __restrict__ X, const float* __restrict__ Wm,
    const float* __restrict__ bias, void* __restrict__ outp, int M, int L) {
  __shared__ unsigned short As[64][40];  // +8 pad: 2-way-max bank aliasing
  __shared__ unsigned short Bs[64][40];
  const int tid = threadIdx.x;
  const int wv = tid >> 6, lane = tid & 63, lg = lane >> 4, lr = lane & 15;
  const int i0 = blockIdx.y * 64, j0 = blockIdx.x * 64;
  const int wr = (wv >> 1) * 32, wc = (wv & 1) * 32;
  const int srow = tid >> 2, scol = (tid & 3) * 8;
  f32x4 acc[2][2] = {};
  const float* xp = X + (size_t)(i0 + srow) * E_DIM + scol;
  const float* wp = Wm + (size_t)(j0 + srow) * E_DIM + scol;
  for (int k0 = 0; k0 < E_DIM; k0 += 32) {
    float4 a1 = *(const float4*)(xp + k0);
    float4 a2 = *(const float4*)(xp + k0 + 4);
    float4 b1 = *(const float4*)(wp + k0);
    float4 b2 = *(const float4*)(wp + k0 + 4);
    __syncthreads();  // protect LDS against previous iteration's reads
    u16x8 av, bv;
    av[0] = f2b(a1.x); av[1] = f2b(a1.y); av[2] = f2b(a1.z); av[3] = f2b(a1.w);
    av[4] = f2b(a2.x); av[5] = f2b(a2.y); av[6] = f2b(a2.z); av[7] = f2b(a2.w);
    bv[0] = f2b(b1.x); bv[1] = f2b(b1.y); bv[2] = f2b(b1.z); bv[3] = f2b(b1.w);
    bv[4] = f2b(b2.x); bv[5] = f2b(b2.y); bv[6] = f2b(b2.z); bv[7] = f2b(b2.w);
    *(u16x8*)&As[srow][scol] = av;
    *(u16x8*)&Bs[srow][scol] = bv;
    __syncthreads();
    bf16x8 af0 = *(const bf16x8*)&As[wr + lr][lg * 8];
    bf16x8 af1 = *(const bf16x8*)&As[wr + 16 + lr][lg * 8];
    bf16x8 bg0 = *(const bf16x8*)&Bs[wc + lr][lg * 8];
    bf16x8 bg1 = *(const bf16x8*)&Bs[wc + 16 + lr][lg * 8];
    acc[0][0] = mfma16(af0, bg0, acc[0][0]);
    acc[0][1] = mfma16(af0, bg1, acc[0][1]);
    acc[1][0] = mfma16(af1, bg0, acc[1][0]);
    acc[1][1] = mfma16(af1, bg1, acc[1][1]);
  }
  for (int mi = 0; mi < 2; ++mi)
    for (int ni = 0; ni < 2; ++ni) {
      const int j = j0 + wc + ni * 16 + lr;
      const float bj = bias[j];
      for (int r = 0; r < 4; ++r) {
        const int i = i0 + wr + mi * 16 + lg * 4 + r;
        const float v = acc[mi][ni][r] + bj;
        if (EPI == 2) {
          ((float*)outp)[(size_t)i * E_DIM + j] = v;
        } else {
          const int bb = i / L, li = i - bb * L;
          const int hh = j >> 6, dd = j & 63;
          if (EPI == 0)
            ((unsigned short*)outp)[((size_t)(bb * NH + hh) * L + li) * HD + dd] = f2b(v);
          else
            ((unsigned short*)outp)[((size_t)(bb * NH + hh) * HD + dd) * L + li] = f2b(v);
        }
      }
    }
}

// One block = (batch b, 16 q-rows), 8 waves = 8 heads. Two-pass softmax.
__global__ __launch_bounds__(512) void attn_kernel(
    const unsigned short* __restrict__ Qb, const unsigned short* __restrict__ Kb,
    const unsigned short* __restrict__ Vt, float* __restrict__ attn_w,
    float* __restrict__ ctx) {
  __shared__ unsigned short P_lds[NH][16][40];  // padded: C-layout -> A-layout
  __shared__ float avgbuf[NH][16][32];
  const int b = blockIdx.y;
  const int q0 = blockIdx.x * 16;
  const int tid = threadIdx.x;
  const int h = tid >> 6, lane = tid & 63, lg = lane >> 4, lr = lane & 15;
  const float scale = 0.125f;  // 1/sqrt(64)

  const unsigned short* Qp = Qb + ((size_t)(b * NH + h) * LQ + q0 + lr) * HD;
  const bf16x8 qf0 = *(const bf16x8*)(Qp + lg * 8);
  const bf16x8 qf1 = *(const bf16x8*)(Qp + 32 + lg * 8);
  const unsigned short* Kp = Kb + (size_t)(b * NH + h) * LKV * HD;
  const unsigned short* Vp = Vt + (size_t)(b * NH + h) * HD * LKV;

  // ---- pass 1: per-lane online max/sumexp over this lane's kv columns ----
  float mrun[4] = {-1e30f, -1e30f, -1e30f, -1e30f};
  float lrun[4] = {0.f, 0.f, 0.f, 0.f};
  for (int kvt = 0; kvt < LKV / 32; ++kvt) {
    const unsigned short* Krow = Kp + ((size_t)kvt * 32 + lr) * HD + lg * 8;
    f32x4 s0 = {}, s1 = {};
    s0 = mfma16(qf0, *(const bf16x8*)(Krow), s0);
    s0 = mfma16(qf1, *(const bf16x8*)(Krow + 32), s0);
    s1 = mfma16(qf0, *(const bf16x8*)(Krow + 16 * HD), s1);
    s1 = mfma16(qf1, *(const bf16x8*)(Krow + 16 * HD + 32), s1);
    for (int r = 0; r < 4; ++r) {
      const float v0 = s0[r] * scale, v1 = s1[r] * scale;
      const float nm = fmaxf(mrun[r], fmaxf(v0, v1));
      lrun[r] = lrun[r] * __expf(mrun[r] - nm) + __expf(v0 - nm) + __expf(v1 - nm);
      mrun[r] = nm;
    }
  }
  // combine across the 16 kv-lanes (xor masks stay inside the 16-lane group)
  float linv[4];
  for (int r = 0; r < 4; ++r) {
    float mm = mrun[r], ll = lrun[r];
    for (int off = 1; off <= 8; off <<= 1) {
      const float om = __shfl_xor(mm, off);
      const float ol = __shfl_xor(ll, off);
      const float nm = fmaxf(mm, om);
      ll = ll * __expf(mm - nm) + ol * __expf(om - nm);
      mm = nm;
    }
    mrun[r] = mm;
    linv[r] = 1.0f / ll;
  }

  // ---- pass 2: recompute scores, emit normalized P, PV, head-avg ----
  f32x4 cacc[4] = {};
  for (int kvt = 0; kvt < LKV / 32; ++kvt) {
    const int kv0 = kvt * 32;
    const unsigned short* Krow = Kp + ((size_t)kv0 + lr) * HD + lg * 8;
    f32x4 s0 = {}, s1 = {};
    s0 = mfma16(qf0, *(const bf16x8*)(Krow), s0);
    s0 = mfma16(qf1, *(const bf16x8*)(Krow + 32), s0);
    s1 = mfma16(qf0, *(const bf16x8*)(Krow + 16 * HD), s1);
    s1 = mfma16(qf1, *(const bf16x8*)(Krow + 16 * HD + 32), s1);
    float avg0[4], avg1[4];
    for (int r = 0; r < 4; ++r) {
      const float p0 = __expf(s0[r] * scale - mrun[r]) * linv[r];
      const float p1 = __expf(s1[r] * scale - mrun[r]) * linv[r];
      avg0[r] = p0;
      avg1[r] = p1;
      P_lds[h][lg * 4 + r][lr] = f2b(p0);
      P_lds[h][lg * 4 + r][16 + lr] = f2b(p1);
    }
    const bf16x8 pf = *(const bf16x8*)&P_lds[h][lr][lg * 8];
    for (int dc = 0; dc < 4; ++dc) {
      const bf16x8 vf =
          *(const bf16x8*)(Vp + (size_t)(dc * 16 + lr) * LKV + kv0 + lg * 8);
      cacc[dc] = mfma16(pf, vf, cacc[dc]);
    }
    for (int r = 0; r < 4; ++r) {
      avgbuf[h][lg * 4 + r][lr] = avg0[r];
      avgbuf[h][lg * 4 + r][16 + lr] = avg1[r];
    }
    __syncthreads();
    {
      const int qq = tid >> 5, kk = tid & 31;  // 512 threads -> 16x32 elems
      float sm = 0.f;
      for (int ww = 0; ww < NH; ++ww) sm += avgbuf[ww][qq][kk];
      attn_w[(size_t)(b * LQ + q0 + qq) * LKV + kv0 + kk] = sm * 0.125f;
    }
    __syncthreads();
  }
  for (int dc = 0; dc < 4; ++dc)
    for (int r = 0; r < 4; ++r)
      ctx[(size_t)(b * LQ + q0 + lg * 4 + r) * E_DIM + h * HD + dc * 16 + lr] =
          cacc[dc][r];
}

// out = LN(query + attn_out) * gamma + beta ; one block per row
__global__ __launch_bounds__(256) void ln_kernel(
    const float* __restrict__ q, const float* __restrict__ ao,
    const float* __restrict__ gamma, const float* __restrict__ beta,
    float* __restrict__ out) {
  const int row = blockIdx.x;
  const int tid = threadIdx.x;
  const size_t base = (size_t)row * E_DIM;
  const float x0 = q[base + tid] + ao[base + tid];
  const float x1 = q[base + 256 + tid] + ao[base + 256 + tid];
  float s = x0 + x1, ss = x0 * x0 + x1 * x1;
  for (int off = 32; off >= 1; off >>= 1) {
    s += __shfl_down(s, off);
    ss += __shfl_down(ss, off);
  }
  __shared__ float ps[4], pss[4];
  if ((tid & 63) == 0) {
    ps[tid >> 6] = s;
    pss[tid >> 6] = ss;
  }
  __syncthreads();
  s = ps[0] + ps[1] + ps[2] + ps[3];
  ss = pss[0] + pss[1] + pss[2] + pss[3];
  const float mu = s * (1.f / E_DIM);
  float var = ss * (1.f / E_DIM) - mu * mu;
  var = fmaxf(var, 0.f);
  const float rstd = rsqrtf(var + 1e-5f);
  out[base + tid] = (x0 - mu) * rstd * gamma[tid] + beta[tid];
  out[base + 256 + tid] = (x1 - mu) * rstd * gamma[256 + tid] + beta[256 + tid];
}

}  // namespace

extern "C" void kernel_launch(void* const* d_in, const int* in_sizes, int n_in,
                              void* d_out, int out_size, void* d_ws, size_t ws_size,
                              hipStream_t stream) {
  const float* query = (const float*)d_in[0];
  const float* key_value = (const float*)d_in[1];
  const float* w_q = (const float*)d_in[2];
  const float* w_k = (const float*)d_in[3];
  const float* w_v = (const float*)d_in[4];
  const float* b_q = (const float*)d_in[5];
  const float* b_k = (const float*)d_in[6];
  const float* b_v = (const float*)d_in[7];
  const float* w_o = (const float*)d_in[8];
  const float* b_o = (const float*)d_in[9];
  const float* ln_g = (const float*)d_in[10];
  const float* ln_b = (const float*)d_in[11];

  // workspace: Qb 4MB | Kb 16MB | Vt 16MB | ctx 8MB | ao 8MB  (52 MB total)
  unsigned short* Qb = (unsigned short*)d_ws;
  unsigned short* Kb = Qb + (size_t)NB * NH * LQ * HD;
  unsigned short* Vt = Kb + (size_t)NB * NH * LKV * HD;
  float* ctx = (float*)(Vt + (size_t)NB * NH * LKV * HD);
  float* ao = ctx + (size_t)NB * LQ * E_DIM;

  float* out = (float*)d_out;
  float* attn_w = out + (size_t)NB * LQ * E_DIM;

  dim3 blk(256);
  gemm_proj<0><<<dim3(8, (NB * LQ) / 64), blk, 0, stream>>>(query, w_q, b_q, Qb,
                                                            NB * LQ, LQ);
  gemm_proj<0><<<dim3(8, (NB * LKV) / 64), blk, 0, stream>>>(key_value, w_k, b_k,
                                                             Kb, NB * LKV, LKV);
  gemm_proj<1><<<dim3(8, (NB * LKV) / 64), blk, 0, stream>>>(key_value, w_v, b_v,
                                                             Vt, NB * LKV, LKV);
  attn_kernel<<<dim3(LQ / 16, NB), dim3(512), 0, stream>>>(Qb, Kb, Vt, attn_w,
                                                           ctx);
  gemm_proj<2><<<dim3(8, (NB * LQ) / 64), blk, 0, stream>>>(ctx, w_o, b_o, ao,
                                                            NB * LQ, LQ);
  ln_kernel<<<dim3(NB * LQ), blk, 0, stream>>>(query, ao, ln_g, ln_b, out);
}

// Round 2
// 295.705 us; speedup vs baseline: 1.7209x; 1.7209x over previous
//
#include <hip/hip_runtime.h>
#include <hip/hip_bf16.h>

namespace {

constexpr int E_DIM = 512;
constexpr int NH = 8;
constexpr int HD = 64;
constexpr int LQ = 1024;
constexpr int LKV = 4096;
constexpr int NB = 4;
constexpr int SPLIT = 4;          // kv splits in attn_main
constexpr int SLICE = LKV / SPLIT; // 1024

typedef __attribute__((ext_vector_type(8))) short bf16x8;
typedef __attribute__((ext_vector_type(8))) unsigned short u16x8;
typedef __attribute__((ext_vector_type(4))) float f32x4;

__device__ __forceinline__ f32x4 mfma16(bf16x8 a, bf16x8 b, f32x4 c) {
  return __builtin_amdgcn_mfma_f32_16x16x32_bf16(a, b, c, 0, 0, 0);
}

// f32 -> bf16 bits, round-to-nearest-even (finite inputs only)
__device__ __forceinline__ unsigned short f2b(float f) {
  unsigned int u = __float_as_uint(f);
  u += 0x7FFFu + ((u >> 16) & 1u);
  return (unsigned short)(u >> 16);
}

__device__ __forceinline__ float b2f(short s) {
  return __uint_as_float(((unsigned int)(unsigned short)s) << 16);
}

// out[i,j] = (sum_k X[i,k]*W[j,k] + bias[j]) * oscale   (N = K = 512)
// EPI 0: bf16 head-split  out[((b*NH+h)*L + l)*64 + d]
// EPI 1: bf16 head-split transposed  out[((b*NH+h)*64 + d)*L + l]
// EPI 2: f32 plain  out[i*512 + j]
template <int EPI>
__global__ __launch_bounds__(256) void gemm_proj(
    const float* __restrict__ X, const float* __restrict__ Wm,
    const float* __restrict__ bias, void* __restrict__ outp, int M, int L,
    float oscale) {
  __shared__ unsigned short As[64][40];
  __shared__ unsigned short Bs[64][40];
  const int tid = threadIdx.x;
  const int wv = tid >> 6, lane = tid & 63, lg = lane >> 4, lr = lane & 15;
  const int i0 = blockIdx.y * 64, j0 = blockIdx.x * 64;
  const int wr = (wv >> 1) * 32, wc = (wv & 1) * 32;
  const int srow = tid >> 2, scol = (tid & 3) * 8;
  f32x4 acc[2][2] = {};
  const float* xp = X + (size_t)(i0 + srow) * E_DIM + scol;
  const float* wp = Wm + (size_t)(j0 + srow) * E_DIM + scol;
  for (int k0 = 0; k0 < E_DIM; k0 += 32) {
    float4 a1 = *(const float4*)(xp + k0);
    float4 a2 = *(const float4*)(xp + k0 + 4);
    float4 b1 = *(const float4*)(wp + k0);
    float4 b2 = *(const float4*)(wp + k0 + 4);
    __syncthreads();
    u16x8 av, bv;
    av[0] = f2b(a1.x); av[1] = f2b(a1.y); av[2] = f2b(a1.z); av[3] = f2b(a1.w);
    av[4] = f2b(a2.x); av[5] = f2b(a2.y); av[6] = f2b(a2.z); av[7] = f2b(a2.w);
    bv[0] = f2b(b1.x); bv[1] = f2b(b1.y); bv[2] = f2b(b1.z); bv[3] = f2b(b1.w);
    bv[4] = f2b(b2.x); bv[5] = f2b(b2.y); bv[6] = f2b(b2.z); bv[7] = f2b(b2.w);
    *(u16x8*)&As[srow][scol] = av;
    *(u16x8*)&Bs[srow][scol] = bv;
    __syncthreads();
    bf16x8 af0 = *(const bf16x8*)&As[wr + lr][lg * 8];
    bf16x8 af1 = *(const bf16x8*)&As[wr + 16 + lr][lg * 8];
    bf16x8 bg0 = *(const bf16x8*)&Bs[wc + lr][lg * 8];
    bf16x8 bg1 = *(const bf16x8*)&Bs[wc + 16 + lr][lg * 8];
    acc[0][0] = mfma16(af0, bg0, acc[0][0]);
    acc[0][1] = mfma16(af0, bg1, acc[0][1]);
    acc[1][0] = mfma16(af1, bg0, acc[1][0]);
    acc[1][1] = mfma16(af1, bg1, acc[1][1]);
  }
  for (int mi = 0; mi < 2; ++mi)
    for (int ni = 0; ni < 2; ++ni) {
      const int j = j0 + wc + ni * 16 + lr;
      const float bj = bias[j];
      for (int r = 0; r < 4; ++r) {
        const int i = i0 + wr + mi * 16 + lg * 4 + r;
        const float v = (acc[mi][ni][r] + bj) * oscale;
        if (EPI == 2) {
          ((float*)outp)[(size_t)i * E_DIM + j] = v;
        } else {
          const int bb = i / L, li = i - bb * L;
          const int hh = j >> 6, dd = j & 63;
          if (EPI == 0)
            ((unsigned short*)outp)[((size_t)(bb * NH + hh) * L + li) * HD + dd] = f2b(v);
          else
            ((unsigned short*)outp)[((size_t)(bb * NH + hh) * HD + dd) * L + li] = f2b(v);
        }
      }
    }
}

// Pass 1: l[b,h,q] = sum_kv exp(score). Q is pre-scaled by 1/8 at projection.
// grid (8=qt*2+sp, NH, NB), 512 thr. wave = 32 q-rows; kv half per block.
__global__ __launch_bounds__(512, 2) void attn_sums(
    const unsigned short* __restrict__ Qb, const unsigned short* __restrict__ Kb,
    float* __restrict__ l_arr) {
  const int tid = threadIdx.x;
  const int w = tid >> 6, lane = tid & 63, lg = lane >> 4, lr = lane & 15;
  const int qt = blockIdx.x >> 1, sp = blockIdx.x & 1;
  const int h = blockIdx.y, b = blockIdx.z;
  const int q0 = qt * 256 + w * 32;
  const size_t bh = (size_t)b * NH + h;
  const unsigned short* Qp = Qb + (bh * LQ + q0) * HD;
  const unsigned short* Kp = Kb + bh * LKV * HD;
  bf16x8 qf[2][2];
  for (int qs = 0; qs < 2; ++qs)
    for (int kk = 0; kk < 2; ++kk)
      qf[qs][kk] = *(const bf16x8*)(Qp + (qs * 16 + lr) * HD + kk * 32 + lg * 8);
  float lsum[2][4] = {};
  for (int t = 0; t < 32; ++t) {
    const int kv0 = sp * 2048 + t * 64;
    bf16x8 kf[4][2];
    for (int ks = 0; ks < 4; ++ks)
      for (int kk = 0; kk < 2; ++kk)
        kf[ks][kk] = *(const bf16x8*)(Kp + (size_t)(kv0 + ks * 16 + lr) * HD +
                                      kk * 32 + lg * 8);
    f32x4 sacc[2][4] = {};
    for (int qs = 0; qs < 2; ++qs)
      for (int ks = 0; ks < 4; ++ks)
        sacc[qs][ks] =
            mfma16(qf[qs][1], kf[ks][1], mfma16(qf[qs][0], kf[ks][0], sacc[qs][ks]));
    for (int qs = 0; qs < 2; ++qs)
      for (int r = 0; r < 4; ++r) {
        const float e0 = __expf(sacc[qs][0][r]) + __expf(sacc[qs][1][r]);
        const float e1 = __expf(sacc[qs][2][r]) + __expf(sacc[qs][3][r]);
        lsum[qs][r] += e0 + e1;
      }
  }
  for (int qs = 0; qs < 2; ++qs)
    for (int r = 0; r < 4; ++r) {
      float v = lsum[qs][r];
      v += __shfl_xor(v, 1);
      v += __shfl_xor(v, 2);
      v += __shfl_xor(v, 4);
      v += __shfl_xor(v, 8);
      if (lr == 0) atomicAdd(&l_arr[bh * LQ + q0 + qs * 16 + lg * 4 + r], v);
    }
}

// Pass 2: normalized P (bf16, XOR-swizzled LDS), PV partial, head-avg attn_w.
// grid (LQ/64, NB, SPLIT), 512 thr. wave = head, 64 q-rows, 1024 kv slice.
__global__ __launch_bounds__(512, 2) void attn_main(
    const unsigned short* __restrict__ Qb, const unsigned short* __restrict__ Kb,
    const unsigned short* __restrict__ Vt, const float* __restrict__ l_arr,
    float* __restrict__ attn_w, float* __restrict__ ctxp) {
  __shared__ __align__(16) unsigned short P_lds[NH][64][80];
  const int tid = threadIdx.x;
  const int h = tid >> 6, lane = tid & 63, lg = lane >> 4, lr = lane & 15;
  const int q0 = blockIdx.x * 64, b = blockIdx.y, sp = blockIdx.z;
  const size_t bh = (size_t)b * NH + h;
  const unsigned short* Qp = Qb + (bh * LQ + q0) * HD;
  const unsigned short* Kp = Kb + bh * LKV * HD;
  const unsigned short* Vp = Vt + bh * HD * LKV;

  bf16x8 qf[4][2];
  for (int qs = 0; qs < 4; ++qs)
    for (int kk = 0; kk < 2; ++kk)
      qf[qs][kk] = *(const bf16x8*)(Qp + (qs * 16 + lr) * HD + kk * 32 + lg * 8);
  float lv[4][4];
  for (int qs = 0; qs < 4; ++qs)
    for (int r = 0; r < 4; ++r)
      lv[qs][r] = 1.0f / l_arr[bh * LQ + q0 + qs * 16 + lg * 4 + r];

  f32x4 cacc[4][4] = {};
  for (int t = 0; t < SLICE / 64; ++t) {
    const int kv0 = sp * SLICE + t * 64;
    bf16x8 kf[4][2];
    for (int ks = 0; ks < 4; ++ks)
      for (int kk = 0; kk < 2; ++kk)
        kf[ks][kk] = *(const bf16x8*)(Kp + (size_t)(kv0 + ks * 16 + lr) * HD +
                                      kk * 32 + lg * 8);
    // scores -> normalized bf16 P into swizzled LDS (half the kv tile at a time)
    for (int kh = 0; kh < 2; ++kh) {
      f32x4 sacc[4][2] = {};
      for (int qs = 0; qs < 4; ++qs)
        for (int k2 = 0; k2 < 2; ++k2) {
          const int ks = kh * 2 + k2;
          sacc[qs][k2] = mfma16(qf[qs][1], kf[ks][1],
                                mfma16(qf[qs][0], kf[ks][0], sacc[qs][k2]));
        }
      for (int qs = 0; qs < 4; ++qs)
        for (int k2 = 0; k2 < 2; ++k2) {
          const int ks = kh * 2 + k2;
          for (int r = 0; r < 4; ++r) {
            const int q = qs * 16 + lg * 4 + r;
            const float p = __expf(sacc[qs][k2][r]) * lv[qs][r];
            const int po = (ks * 2 + (lr >> 3)) ^ (q & 7);
            P_lds[h][q][po * 8 + (lr & 7)] = f2b(p);
          }
        }
    }
    // PV: own-head P (wave-local, no barrier needed before this)
    for (int kk = 0; kk < 2; ++kk) {
      bf16x8 pa[4], vf[4];
      for (int qs = 0; qs < 4; ++qs)
        pa[qs] = *(const bf16x8*)&P_lds[h][qs * 16 + lr]
                                       [((kk * 4 + lg) ^ (lr & 7)) * 8];
      for (int ds = 0; ds < 4; ++ds)
        vf[ds] = *(const bf16x8*)(Vp + (size_t)(ds * 16 + lr) * LKV + kv0 +
                                  kk * 32 + lg * 8);
      for (int qs = 0; qs < 4; ++qs)
        for (int ds = 0; ds < 4; ++ds)
          cacc[qs][ds] = mfma16(pa[qs], vf[ds], cacc[qs][ds]);
    }
    __syncthreads();
    // head-average -> attn_w (each thread: one q-row, 8 kv)
    {
      const int qa = tid >> 3, La = tid & 7;
      const int po = La ^ (qa & 7);
      float s[8] = {};
      for (int hh = 0; hh < NH; ++hh) {
        const bf16x8 v = *(const bf16x8*)&P_lds[hh][qa][po * 8];
        for (int j = 0; j < 8; ++j) s[j] += b2f(v[j]);
      }
      float* op = attn_w + (size_t)(b * LQ + q0 + qa) * LKV + kv0 + La * 8;
      float4 o0 = {s[0] * 0.125f, s[1] * 0.125f, s[2] * 0.125f, s[3] * 0.125f};
      float4 o1 = {s[4] * 0.125f, s[5] * 0.125f, s[6] * 0.125f, s[7] * 0.125f};
      *(float4*)op = o0;
      *(float4*)(op + 4) = o1;
    }
    __syncthreads();
  }
  float* cp = ctxp + (size_t)sp * (NB * LQ * E_DIM);
  for (int qs = 0; qs < 4; ++qs)
    for (int ds = 0; ds < 4; ++ds)
      for (int r = 0; r < 4; ++r)
        cp[(size_t)(b * LQ + q0 + qs * 16 + lg * 4 + r) * E_DIM + h * HD +
           ds * 16 + lr] = cacc[qs][ds][r];
}

// ctxp[0] += ctxp[1..3]  (in place into plane 0)
__global__ __launch_bounds__(256) void combine_ctx(float* __restrict__ ctxp) {
  const size_t i = ((size_t)blockIdx.x * 256 + threadIdx.x) * 4;
  constexpr size_t PL = (size_t)NB * LQ * E_DIM;
  float4 a = *(float4*)(ctxp + i);
  float4 b = *(float4*)(ctxp + PL + i);
  float4 c = *(float4*)(ctxp + 2 * PL + i);
  float4 d = *(float4*)(ctxp + 3 * PL + i);
  float4 o = {a.x + b.x + c.x + d.x, a.y + b.y + c.y + d.y,
              a.z + b.z + c.z + d.z, a.w + b.w + c.w + d.w};
  *(float4*)(ctxp + i) = o;
}

// out = LN(query + attn_out) * gamma + beta ; one block per row
__global__ __launch_bounds__(256) void ln_kernel(
    const float* __restrict__ q, const float* __restrict__ ao,
    const float* __restrict__ gamma, const float* __restrict__ beta,
    float* __restrict__ out) {
  const int row = blockIdx.x;
  const int tid = threadIdx.x;
  const size_t base = (size_t)row * E_DIM;
  const float x0 = q[base + tid] + ao[base + tid];
  const float x1 = q[base + 256 + tid] + ao[base + 256 + tid];
  float s = x0 + x1, ss = x0 * x0 + x1 * x1;
  for (int off = 32; off >= 1; off >>= 1) {
    s += __shfl_down(s, off);
    ss += __shfl_down(ss, off);
  }
  __shared__ float ps[4], pss[4];
  if ((tid & 63) == 0) {
    ps[tid >> 6] = s;
    pss[tid >> 6] = ss;
  }
  __syncthreads();
  s = ps[0] + ps[1] + ps[2] + ps[3];
  ss = pss[0] + pss[1] + pss[2] + pss[3];
  const float mu = s * (1.f / E_DIM);
  float var = ss * (1.f / E_DIM) - mu * mu;
  var = fmaxf(var, 0.f);
  const float rstd = rsqrtf(var + 1e-5f);
  out[base + tid] = (x0 - mu) * rstd * gamma[tid] + beta[tid];
  out[base + 256 + tid] = (x1 - mu) * rstd * gamma[256 + tid] + beta[256 + tid];
}

}  // namespace

extern "C" void kernel_launch(void* const* d_in, const int* in_sizes, int n_in,
                              void* d_out, int out_size, void* d_ws, size_t ws_size,
                              hipStream_t stream) {
  const float* query = (const float*)d_in[0];
  const float* key_value = (const float*)d_in[1];
  const float* w_q = (const float*)d_in[2];
  const float* w_k = (const float*)d_in[3];
  const float* w_v = (const float*)d_in[4];
  const float* b_q = (const float*)d_in[5];
  const float* b_k = (const float*)d_in[6];
  const float* b_v = (const float*)d_in[7];
  const float* w_o = (const float*)d_in[8];
  const float* b_o = (const float*)d_in[9];
  const float* ln_g = (const float*)d_in[10];
  const float* ln_b = (const float*)d_in[11];

  // ws: Qb 4MB | Kb 16MB | Vt 16MB | l 128KB | ctxp 4x8MB | ao 8MB  (~76 MB)
  unsigned short* Qb = (unsigned short*)d_ws;
  unsigned short* Kb = Qb + (size_t)NB * NH * LQ * HD;
  unsigned short* Vt = Kb + (size_t)NB * NH * LKV * HD;
  float* l_arr = (float*)(Vt + (size_t)NB * NH * LKV * HD);
  float* ctxp = l_arr + (size_t)NB * NH * LQ;
  float* ao = ctxp + (size_t)SPLIT * NB * LQ * E_DIM;

  float* out = (float*)d_out;
  float* attn_w = out + (size_t)NB * LQ * E_DIM;

  hipMemsetAsync(l_arr, 0, sizeof(float) * NB * NH * LQ, stream);

  dim3 blk(256);
  // Q projection folds in the 1/sqrt(64) score scale.
  gemm_proj<0><<<dim3(8, (NB * LQ) / 64), blk, 0, stream>>>(query, w_q, b_q, Qb,
                                                            NB * LQ, LQ, 0.125f);
  gemm_proj<0><<<dim3(8, (NB * LKV) / 64), blk, 0, stream>>>(key_value, w_k, b_k,
                                                             Kb, NB * LKV, LKV, 1.0f);
  gemm_proj<1><<<dim3(8, (NB * LKV) / 64), blk, 0, stream>>>(key_value, w_v, b_v,
                                                             Vt, NB * LKV, LKV, 1.0f);
  attn_sums<<<dim3(8, NH, NB), dim3(512), 0, stream>>>(Qb, Kb, l_arr);
  attn_main<<<dim3(LQ / 64, NB, SPLIT), dim3(512), 0, stream>>>(Qb, Kb, Vt, l_arr,
                                                                attn_w, ctxp);
  combine_ctx<<<dim3((NB * LQ * E_DIM) / (256 * 4)), blk, 0, stream>>>(ctxp);
  gemm_proj<2><<<dim3(8, (NB * LQ) / 64), blk, 0, stream>>>(ctxp, w_o, b_o, ao,
                                                            NB * LQ, LQ, 1.0f);
  ln_kernel<<<dim3(NB * LQ), blk, 0, stream>>>(query, ao, ln_g, ln_b, out);
}